// Round 8
// baseline (1729.707 us; speedup 1.0000x reference)
//
#include <hip/hip_runtime.h>
#include <math.h>

typedef unsigned short ushort_t;
typedef unsigned int uint_t;
typedef __bf16 bf16x4 __attribute__((ext_vector_type(4)));
typedef __bf16 bf16x8 __attribute__((ext_vector_type(8)));
typedef float f32x4 __attribute__((ext_vector_type(4)));

#define T_SEQ   1536
#define NB      2
#define MROWS   3072
#define DMODEL  512
#define NHEADS  8
#define DHEAD   64
#define DFF     2048
#define DMOTION 256
#define NLAYERS 6
#define PERIODN 15
#define CTXF    10
#define THRW    128
#define KIN     384           // 262 zero-padded to multiple of 128

__device__ __forceinline__ float bf2f(ushort_t u) { return __uint_as_float((uint_t)u << 16); }
__device__ __forceinline__ ushort_t f2bf(float f) {
    uint_t x = __float_as_uint(f);
    return (ushort_t)((x + 0x7fffu + ((x >> 16) & 1u)) >> 16);   // RNE
}

// ---------------------------------------------------------------------------
// PE table (15 distinct rows)
// ---------------------------------------------------------------------------
__global__ __launch_bounds__(256) void pe_k(float* __restrict__ pe) {
    int idx = blockIdx.x * 256 + threadIdx.x;
    if (idx >= PERIODN * DMODEL) return;
    int p = idx / DMODEL, c = idx % DMODEL;
    int j = (c < DMODEL / 2) ? c : (c - DMODEL / 2);
    float div = __expf(-logf(10000.0f) * (2.0f * (float)j) / (float)DMODEL);
    float ang = (float)p * div;
    pe[idx] = (c < DMODEL / 2) ? sinf(ang) : cosf(ang);
}

// ---------------------------------------------------------------------------
// Encoder input (bf16, K padded to 384) + mask output
// ---------------------------------------------------------------------------
__global__ __launch_bounds__(256) void build_k(const float* __restrict__ motion,
                                               const float* __restrict__ traj,
                                               ushort_t* __restrict__ hin,
                                               float* __restrict__ mask_out) {
    int idx = blockIdx.x * 256 + threadIdx.x;
    if (idx >= MROWS * KIN) return;
    int row = idx / KIN, c = idx % KIN;
    int t = row % T_SEQ;
    float mv = (t < CTXF || t == T_SEQ - 1) ? 1.0f : 0.0f;
    float val;
    if (c < DMOTION)            val = motion[(size_t)row * DMOTION + c] * mv;
    else if (c < DMOTION + 5)   val = traj[(size_t)row * 5 + (c - DMOTION)];
    else if (c == DMOTION + 5)  val = mv;
    else                        val = 0.0f;
    hin[idx] = f2bf(val);
    if (c == 0) mask_out[row] = mv;
}

// ---------------------------------------------------------------------------
// Transpose-convert: src f32 [K][N] -> dst bf16 [N][Kpad] (zero pad k>=K).
// ---------------------------------------------------------------------------
__global__ __launch_bounds__(256)
void tconv_k(const float* __restrict__ src, size_t sstride,
             ushort_t* __restrict__ dst, size_t dstride,
             int K, int N, int Kpad) {
    __shared__ float t[32][33];
    src += (size_t)blockIdx.z * sstride;
    dst += (size_t)blockIdx.z * dstride;
    const int kb = blockIdx.y * 32, nb = blockIdx.x * 32;
    const int tx = threadIdx.x & 31, ty = threadIdx.x >> 5;
#pragma unroll
    for (int i = 0; i < 4; ++i) {
        int k = kb + ty + i * 8, n = nb + tx;
        t[ty + i * 8][tx] = (k < K && n < N) ? src[(size_t)k * N + n] : 0.0f;
    }
    __syncthreads();
#pragma unroll
    for (int i = 0; i < 4; ++i) {
        int n = nb + ty + i * 8, kk = kb + tx;
        if (n < N && kk < Kpad) dst[(size_t)n * Kpad + kk] = f2bf(t[tx][ty + i * 8]);
    }
}

// QKV concat transpose: z = layer*3+seg; dst = qkvt[l][seg*512 + n][k]
__global__ __launch_bounds__(256)
void tconv_qkv_k(const float* __restrict__ wq, const float* __restrict__ wk,
                 const float* __restrict__ wv, ushort_t* __restrict__ qkvt) {
    __shared__ float t[32][33];
    const int z = blockIdx.z, s = z % 3, l = z / 3;
    const float* src = (s == 0 ? wq : s == 1 ? wk : wv) + (size_t)l * DMODEL * DMODEL;
    ushort_t* dst = qkvt + (size_t)z * DMODEL * DMODEL;
    const int kb = blockIdx.y * 32, nb = blockIdx.x * 32;
    const int tx = threadIdx.x & 31, ty = threadIdx.x >> 5;
#pragma unroll
    for (int i = 0; i < 4; ++i)
        t[ty + i * 8][tx] = src[(size_t)(kb + ty + i * 8) * DMODEL + nb + tx];
    __syncthreads();
#pragma unroll
    for (int i = 0; i < 4; ++i)
        dst[(size_t)(nb + ty + i * 8) * DMODEL + kb + tx] = f2bf(t[tx][ty + i * 8]);
}

__global__ __launch_bounds__(256)
void bcat_k(const float* __restrict__ bq, const float* __restrict__ bk,
            const float* __restrict__ bv, float* __restrict__ bqkv) {
    int idx = blockIdx.x * 256 + threadIdx.x;
    if (idx >= NLAYERS * 3 * DMODEL) return;
    int l = idx / (3 * DMODEL), n = idx % (3 * DMODEL);
    int s = n >> 9, c = n & 511;
    const float* b = (s == 0 ? bq : s == 1 ? bk : bv);
    bqkv[idx] = b[l * DMODEL + c];
}

// ---------------------------------------------------------------------------
// Split-K bf16 MFMA GEMM: C[M,N] = epi(A[M,K] @ Wt[N,K]^T + bias)
// 32x128 tile, 4 waves each owning a 32-wide k-slice of a BK=128 chunk.
// 16 MFMA per wave per barrier-pair (2x vs 32x64). Transient reg staging.
// LDS rows 272 B -> frag reads ~2-way (free). 2-stage LDS reduce.
// ---------------------------------------------------------------------------
#define SLD 136     // 128 + 8 pad elems (row = 272 B)
#define CL  132     // f32 reduce-buffer row stride (128 + 4)
template <int ACT, bool RES, bool PE, bool OUTBF>
__global__ __launch_bounds__(256)
void sgemm_k(const ushort_t* __restrict__ A, int K,
             const ushort_t* __restrict__ Wt,
             const float* __restrict__ bias,
             const float* __restrict__ res,
             const float* __restrict__ pe15,
             void* __restrict__ Cout, int N) {
    __shared__ ushort_t smem[(32 + 128) * SLD];   // As | Bs, reused as cb0|cb1
    ushort_t* As = smem;
    ushort_t* Bs = smem + 32 * SLD;
    const int tid = threadIdx.x;
    const int lane = tid & 63, wid = tid >> 6;
    const int m0 = blockIdx.y * 32, n0 = blockIdx.x * 128;
    const int l4 = lane >> 4, l15 = lane & 15;
    const int srow = tid >> 4, scol = (tid & 15) * 8;   // 16 rows x 128 cols per pass

    f32x4 acc[2][8];
#pragma unroll
    for (int m = 0; m < 2; ++m)
#pragma unroll
        for (int n = 0; n < 8; ++n) acc[m][n] = (f32x4){0.f, 0.f, 0.f, 0.f};

    const int niter = K >> 7;                      // K multiple of 128

    for (int it = 0; it < niter; ++it) {
        const int k0 = it << 7;
        // transient staging registers (dead after LDS write)
        uint4 a0 = *(const uint4*)(A  + (size_t)(m0 + srow)      * K + k0 + scol);
        uint4 a1 = *(const uint4*)(A  + (size_t)(m0 + 16 + srow) * K + k0 + scol);
        uint4 br[8];
#pragma unroll
        for (int j = 0; j < 8; ++j)
            br[j] = *(const uint4*)(Wt + (size_t)(n0 + j * 16 + srow) * K + k0 + scol);
        __syncthreads();                           // prior reads done
        *(uint4*)&As[srow * SLD + scol]        = a0;
        *(uint4*)&As[(16 + srow) * SLD + scol] = a1;
#pragma unroll
        for (int j = 0; j < 8; ++j)
            *(uint4*)&Bs[(j * 16 + srow) * SLD + scol] = br[j];
        __syncthreads();                           // tile staged

        const int kb = wid * 32;                   // this wave's k-slice
        bf16x8 af[2], bf[8];
#pragma unroll
        for (int m = 0; m < 2; ++m) {
            const ushort_t* p = &As[(m * 16 + l15) * SLD + kb];
            bf16x4 lo4 = *(const bf16x4*)(p + l4 * 4);
            bf16x4 hi4 = *(const bf16x4*)(p + 16 + l4 * 4);
            af[m] = __builtin_shufflevector(lo4, hi4, 0, 1, 2, 3, 4, 5, 6, 7);
        }
#pragma unroll
        for (int n = 0; n < 8; ++n) {
            const ushort_t* p = &Bs[(n * 16 + l15) * SLD + kb];
            bf16x4 lo4 = *(const bf16x4*)(p + l4 * 4);
            bf16x4 hi4 = *(const bf16x4*)(p + 16 + l4 * 4);
            bf[n] = __builtin_shufflevector(lo4, hi4, 0, 1, 2, 3, 4, 5, 6, 7);
        }
#pragma unroll
        for (int m = 0; m < 2; ++m)
#pragma unroll
            for (int n = 0; n < 8; ++n)
                acc[m][n] = __builtin_amdgcn_mfma_f32_16x16x32_bf16(af[m], bf[n], acc[m][n], 0, 0, 0);
    }

    // ---- cross-wave reduce: waves 2,3 write; waves 0,1 accumulate ----
    float* cb0 = (float*)smem;                     // 32 x CL
    float* cb1 = (float*)smem + 32 * CL;
    __syncthreads();
    if (wid >= 2) {
        float* cb = (wid == 2) ? cb0 : cb1;
#pragma unroll
        for (int m = 0; m < 2; ++m)
#pragma unroll
            for (int n = 0; n < 8; ++n)
#pragma unroll
                for (int r = 0; r < 4; ++r)
                    cb[(m * 16 + l4 * 4 + r) * CL + n * 16 + l15] = acc[m][n][r];
    }
    __syncthreads();
    if (wid < 2) {
        float* cb = (wid == 0) ? cb0 : cb1;
#pragma unroll
        for (int m = 0; m < 2; ++m)
#pragma unroll
            for (int n = 0; n < 8; ++n)
#pragma unroll
                for (int r = 0; r < 4; ++r)
                    cb[(m * 16 + l4 * 4 + r) * CL + n * 16 + l15] += acc[m][n][r];
    }
    __syncthreads();

    // ---- epilogue: thread t -> row t>>3, cols (t&7)*16 .. +15 ----
    const int row = tid >> 3, c0 = (tid & 7) * 16;
    const int grow = m0 + row;
#pragma unroll
    for (int j = 0; j < 16; ++j) {
        const int gcol = n0 + c0 + j;
        float v = cb0[row * CL + c0 + j] + cb1[row * CL + c0 + j] + bias[gcol];
        if (ACT == 1) v = v >= 0.f ? v : 0.01f * v;
        else if (ACT == 2) v = fmaxf(v, 0.f);
        if (PE) v += pe15[((grow % T_SEQ) % PERIODN) * DMODEL + gcol];
        if (RES) v += res[(size_t)grow * N + gcol];
        if (OUTBF) ((ushort_t*)Cout)[(size_t)grow * N + gcol] = f2bf(v);
        else       ((float*)Cout)[(size_t)grow * N + gcol] = v;
    }
}

// ---------------------------------------------------------------------------
// LayerNorm: f32 in, bf16 out. One wave per row.
// ---------------------------------------------------------------------------
__global__ __launch_bounds__(256)
void ln_k(const float* __restrict__ X, const float* __restrict__ g,
          const float* __restrict__ b, ushort_t* __restrict__ Y) {
    const int wid = threadIdx.x >> 6, lane = threadIdx.x & 63;
    const int row = blockIdx.x * 4 + wid;
    const float* x = X + (size_t)row * DMODEL;
    float v[8], s = 0.f;
#pragma unroll
    for (int j = 0; j < 8; ++j) { v[j] = x[lane + 64 * j]; s += v[j]; }
#pragma unroll
    for (int o = 32; o; o >>= 1) s += __shfl_xor(s, o);
    const float mean = s * (1.0f / DMODEL);
    float vs = 0.f;
#pragma unroll
    for (int j = 0; j < 8; ++j) { float d = v[j] - mean; vs += d * d; }
#pragma unroll
    for (int o = 32; o; o >>= 1) vs += __shfl_xor(vs, o);
    const float inv = rsqrtf(vs * (1.0f / DMODEL) + 1e-5f);
    ushort_t* y = Y + (size_t)row * DMODEL;
#pragma unroll
    for (int j = 0; j < 8; ++j) {
        const int c = lane + 64 * j;
        y[c] = f2bf((v[j] - mean) * inv * g[c] + b[c]);
    }
}

// ---------------------------------------------------------------------------
// V-mean partials: grid (16 bh, 8 chunks), 1024 thr. 192 rows per block.
// ---------------------------------------------------------------------------
__global__ __launch_bounds__(1024)
void vmeanp_k(const ushort_t* __restrict__ qkv, float* __restrict__ vmp) {
    __shared__ float red[16][64];
    const int bh = blockIdx.x, ch = blockIdx.y;
    const int b = bh >> 3, h = bh & 7;
    const int wid = threadIdx.x >> 6, lane = threadIdx.x & 63;
    const ushort_t* Vb = qkv + (size_t)(b * T_SEQ) * 1536 + 1024 + h * 64 + lane;
    float s = 0.f;
    const int t0 = ch * 192;
    for (int t = t0 + wid; t < t0 + 192; t += 16) s += bf2f(Vb[(size_t)t * 1536]);
    red[wid][lane] = s;
    __syncthreads();
    if (wid == 0) {
        float tot = 0.f;
#pragma unroll
        for (int i = 0; i < 16; ++i) tot += red[i][lane];
        vmp[(ch * 16 + bh) * 64 + lane] = tot;
    }
}

// Reduce 8 partials -> vm[1024] (= [b][h][d]), scaled by 1/T.
__global__ __launch_bounds__(1024)
void vmred_k(const float* __restrict__ vmp, float* __restrict__ vm) {
    const int t = threadIdx.x;
    float s = 0.f;
#pragma unroll
    for (int ch = 0; ch < 8; ++ch) s += vmp[ch * 1024 + t];
    vm[t] = s * (1.0f / T_SEQ);
}

// Fill inactive rows [q0, q0+grid.x) with vmean.
__global__ __launch_bounds__(256)
void vfill_k(const float* __restrict__ vm, ushort_t* __restrict__ attout, int q0) {
    const int qrow = q0 + blockIdx.x, b = blockIdx.y;
    const int tid = threadIdx.x;
#pragma unroll
    for (int r = 0; r < 2; ++r) {
        const int c = tid + r * 256;
        attout[(size_t)(b * T_SEQ + qrow) * DMODEL + c] = f2bf(vm[b * 512 + c]);
    }
}

// ---------------------------------------------------------------------------
// MFMA flash attention. One WAVE per 16-row q-subtile of an active interval.
// Swapped operands: S^T = mfma(K,Q) -> q = lane&15; O^T = mfma(V^T, P).
// ---------------------------------------------------------------------------
#define KLD 72
#define VLD 36
__global__ __launch_bounds__(256)
void attn3_k(const ushort_t* __restrict__ qkv, ushort_t* __restrict__ attout,
             int lo, int hi, int nlow, int qhi0, int tl, int st) {
    __shared__ ushort_t klds_[4][32 * KLD];
    __shared__ ushort_t vlds_[4][64 * VLD];
    const int lane = threadIdx.x & 63, wid = threadIdx.x >> 6;
    const int s = blockIdx.x * 4 + wid;
    if (s >= st) return;
    const int h = blockIdx.y, b = blockIdx.z;
    const int l15 = lane & 15, l4 = lane >> 4;

    int qb, qend;
    if (s < tl) { qb = 16 * s;                qend = nlow - 1; }
    else        { qb = qhi0 + 16 * (s - tl);  qend = T_SEQ - 1; }
    const int nr = qend - qb;

    ushort_t* klds = klds_[wid];
    ushort_t* vlds = vlds_[wid];
    const size_t rbase = (size_t)(b * T_SEQ) * 1536;
    const int q = qb + l15;

    const int qrow_r = min(q, T_SEQ - 1);
    const ushort_t* qptr = qkv + rbase + (size_t)qrow_r * 1536 + h * 64;
    bf16x8 bq[2];
#pragma unroll
    for (int kh = 0; kh < 2; ++kh) {
        bf16x4 lo4 = *(const bf16x4*)(qptr + kh * 32 + l4 * 4);
        bf16x4 hi4 = *(const bf16x4*)(qptr + kh * 32 + 16 + l4 * 4);
        bq[kh] = __builtin_shufflevector(lo4, hi4, 0, 1, 2, 3, 4, 5, 6, 7);
    }

    const int band0 = max(0, qb - THRW);
    const int band1 = min(T_SEQ - 1, qb + 15 + THRW);
    const int i1s = band0, i1e = min(band1, lo - 1);
    const int i2s = max(band0, hi), i2e = band1;

    f32x4 O[4] = {{0.f,0.f,0.f,0.f},{0.f,0.f,0.f,0.f},{0.f,0.f,0.f,0.f},{0.f,0.f,0.f,0.f}};
    float m = -3.0e38f, lsum = 0.f;

#pragma unroll 1
    for (int seg = 0; seg < 2; ++seg) {
        const int s0 = seg ? i2s : i1s, s1 = seg ? i2e : i1e;
#pragma unroll 1
        for (int c0 = s0; c0 <= s1; c0 += 32) {
#pragma unroll
            for (int i = 0; i < 4; ++i) {
                const int idx = i * 64 + lane;
                const int row = idx >> 3, c = (idx & 7) * 8;
                const int kr = min(c0 + row, T_SEQ - 1);
                const uint4 kv = *(const uint4*)(qkv + rbase + (size_t)kr * 1536 + 512 + h * 64 + c);
                *(uint4*)&klds[row * KLD + c] = kv;
                const uint4 vv = *(const uint4*)(qkv + rbase + (size_t)kr * 1536 + 1024 + h * 64 + c);
                const ushort_t* vp = (const ushort_t*)&vv;
#pragma unroll
                for (int d = 0; d < 8; ++d) vlds[(c + d) * VLD + row] = vp[d];
            }
            f32x4 sacc[2];
#pragma unroll
            for (int ks = 0; ks < 2; ++ks) {
                f32x4 a = {0.f, 0.f, 0.f, 0.f};
#pragma unroll
                for (int kh = 0; kh < 2; ++kh) {
                    const ushort_t* kp = &klds[(16 * ks + l15) * KLD + kh * 32];
                    bf16x4 lo4 = *(const bf16x4*)(kp + l4 * 4);
                    bf16x4 hi4 = *(const bf16x4*)(kp + 16 + l4 * 4);
                    bf16x8 ak = __builtin_shufflevector(lo4, hi4, 0, 1, 2, 3, 4, 5, 6, 7);
                    a = __builtin_amdgcn_mfma_f32_16x16x32_bf16(ak, bq[kh], a, 0, 0, 0);
                }
                sacc[ks] = a;
            }
            float sv[8];
            bool vld[8];
            float cm = -3.0e38f;
#pragma unroll
            for (int ks = 0; ks < 2; ++ks)
#pragma unroll
                for (int r = 0; r < 4; ++r) {
                    const int key = c0 + 16 * ks + 4 * l4 + r;
                    const int dist = (q > key) ? (q - key) : (key - q);
                    const bool v = (dist <= THRW) && (key < lo || key >= hi) && (key < T_SEQ);
                    const int ii = ks * 4 + r;
                    sv[ii] = sacc[ks][r] * 0.125f - (float)(dist / PERIODN);
                    vld[ii] = v;
                    cm = fmaxf(cm, v ? sv[ii] : -3.0e38f);
                }
            cm = fmaxf(cm, __shfl_xor(cm, 16));
            cm = fmaxf(cm, __shfl_xor(cm, 32));
            const float mnew = fmaxf(m, cm);
            const float sc = __expf(m - mnew);
            m = mnew;
            float p[8], psum = 0.f;
#pragma unroll
            for (int ii = 0; ii < 8; ++ii) {
                p[ii] = vld[ii] ? __expf(sv[ii] - mnew) : 0.f;
                psum += p[ii];
            }
            psum += __shfl_xor(psum, 16);
            psum += __shfl_xor(psum, 32);
            lsum = lsum * sc + psum;
#pragma unroll
            for (int ds = 0; ds < 4; ++ds) O[ds] *= sc;
            bf16x8 pb;
#pragma unroll
            for (int ii = 0; ii < 8; ++ii) pb[ii] = (__bf16)p[ii];
#pragma unroll
            for (int ds = 0; ds < 4; ++ds) {
                const ushort_t* vp2 = &vlds[(16 * ds + l15) * VLD];
                bf16x4 lo4 = *(const bf16x4*)(vp2 + 4 * l4);
                bf16x4 hi4 = *(const bf16x4*)(vp2 + 16 + 4 * l4);
                bf16x8 av = __builtin_shufflevector(lo4, hi4, 0, 1, 2, 3, 4, 5, 6, 7);
                O[ds] = __builtin_amdgcn_mfma_f32_16x16x32_bf16(av, pb, O[ds], 0, 0, 0);
            }
        }
    }
    if (l15 <= nr) {
        const float inv = 1.0f / lsum;
        ushort_t* op = attout + (size_t)(b * T_SEQ + qb + l15) * DMODEL + h * 64;
#pragma unroll
        for (int ds = 0; ds < 4; ++ds)
#pragma unroll
            for (int r = 0; r < 4; ++r)
                op[16 * ds + 4 * l4 + r] = f2bf(O[ds][r] * inv);
    }
}

// ---------------------------------------------------------------------------
// Final blend
// ---------------------------------------------------------------------------
__global__ __launch_bounds__(256)
void final_k(const float* __restrict__ motion, const float* __restrict__ xdec,
             float* __restrict__ out) {
    int idx = blockIdx.x * 256 + threadIdx.x;
    if (idx >= MROWS * DMOTION) return;
    const int row = idx >> 8;
    const int t = row % T_SEQ;
    const float mv = (t < CTXF || t == T_SEQ - 1) ? 1.0f : 0.0f;
    out[idx] = motion[idx] * mv + xdec[idx] * (1.0f - mv);
}

// ---------------------------------------------------------------------------
extern "C" void kernel_launch(void* const* d_in, const int* in_sizes, int n_in,
                              void* d_out, int out_size, void* d_ws, size_t ws_size,
                              hipStream_t stream) {
    const float* motion = (const float*)d_in[0];
    const float* traj   = (const float*)d_in[1];
    const float* me_w1  = (const float*)d_in[2];
    const float* me_b1  = (const float*)d_in[3];
    const float* me_w2  = (const float*)d_in[4];
    const float* me_b2  = (const float*)d_in[5];
    const float* wq = (const float*)d_in[6];
    const float* bq = (const float*)d_in[7];
    const float* wk = (const float*)d_in[8];
    const float* bk = (const float*)d_in[9];
    const float* wv = (const float*)d_in[10];
    const float* bv = (const float*)d_in[11];
    const float* wo = (const float*)d_in[12];
    const float* bo = (const float*)d_in[13];
    const float* ln1_g = (const float*)d_in[14];
    const float* ln1_b = (const float*)d_in[15];
    const float* ffn_w1 = (const float*)d_in[16];
    const float* ffn_b1 = (const float*)d_in[17];
    const float* ffn_w2 = (const float*)d_in[18];
    const float* ffn_b2 = (const float*)d_in[19];
    const float* ln2_g = (const float*)d_in[20];
    const float* ln2_b = (const float*)d_in[21];
    const float* fln_g = (const float*)d_in[22];
    const float* fln_b = (const float*)d_in[23];
    const float* dec_w1 = (const float*)d_in[24];
    const float* dec_b1 = (const float*)d_in[25];
    const float* dec_w2 = (const float*)d_in[26];
    const float* dec_b2 = (const float*)d_in[27];

    float* out = (float*)d_out;
    float* mask_out = out + (size_t)MROWS * DMOTION;

    char* base = (char*)d_ws;
    auto alloc = [&](size_t bytes) { char* p = base; base += (bytes + 255) & ~(size_t)255; return p; };

    ushort_t* qkvt  = (ushort_t*)alloc((size_t)NLAYERS * 1536 * 512 * 2);
    ushort_t* wot   = (ushort_t*)alloc((size_t)NLAYERS * 512 * 512 * 2);
    ushort_t* ffn1t = (ushort_t*)alloc((size_t)NLAYERS * 2048 * 512 * 2);
    ushort_t* ffn2t = (ushort_t*)alloc((size_t)NLAYERS * 512 * 2048 * 2);
    ushort_t* mew1t = (ushort_t*)alloc((size_t)512 * KIN * 2);
    ushort_t* mew2t = (ushort_t*)alloc((size_t)512 * 512 * 2);
    ushort_t* dec1t = (ushort_t*)alloc((size_t)512 * 512 * 2);
    ushort_t* dec2t = (ushort_t*)alloc((size_t)256 * 512 * 2);
    float*    bqkv  = (float*)alloc((size_t)NLAYERS * 1536 * 4);
    float*    pe15  = (float*)alloc((size_t)PERIODN * DMODEL * 4);
    float*    vmp   = (float*)alloc((size_t)8 * 16 * 64 * 4);
    float*    vm    = (float*)alloc((size_t)16 * 64 * 4);
    ushort_t* hin   = (ushort_t*)alloc((size_t)MROWS * KIN * 2);
    float*    x     = (float*)alloc((size_t)MROWS * DMODEL * 4);
    ushort_t* h     = (ushort_t*)alloc((size_t)MROWS * DMODEL * 2);
    ushort_t* qkv   = (ushort_t*)alloc((size_t)MROWS * 1536 * 2);
    ushort_t* ff    = (ushort_t*)alloc((size_t)MROWS * DFF * 2);
    float*    xdec  = (float*)qkv;   // alias: qkv dead after last attn

    const dim3 blk(256);
    pe_k<<<(PERIODN * DMODEL + 255) / 256, blk, 0, stream>>>(pe15);
    build_k<<<(MROWS * KIN + 255) / 256, blk, 0, stream>>>(motion, traj, hin, mask_out);

    tconv_qkv_k<<<dim3(16, 16, 18), blk, 0, stream>>>(wq, wk, wv, qkvt);
    tconv_k<<<dim3(16, 16, 6), blk, 0, stream>>>(wo, 512 * 512, wot, 512 * 512, 512, 512, 512);
    tconv_k<<<dim3(64, 16, 6), blk, 0, stream>>>(ffn_w1, 512 * 2048, ffn1t, 2048 * 512, 512, 2048, 512);
    tconv_k<<<dim3(16, 64, 6), blk, 0, stream>>>(ffn_w2, 2048 * 512, ffn2t, 512 * 2048, 2048, 512, 2048);
    tconv_k<<<dim3(16, 12, 1), blk, 0, stream>>>(me_w1, 0, mew1t, 0, 262, 512, KIN);
    tconv_k<<<dim3(16, 16, 1), blk, 0, stream>>>(me_w2, 0, mew2t, 0, 512, 512, 512);
    tconv_k<<<dim3(16, 16, 1), blk, 0, stream>>>(dec_w1, 0, dec1t, 0, 512, 512, 512);
    tconv_k<<<dim3(8, 16, 1),  blk, 0, stream>>>(dec_w2, 0, dec2t, 0, 512, 256, 512);
    bcat_k<<<(NLAYERS * 1536 + 255) / 256, blk, 0, stream>>>(bq, bk, bv, bqkv);

    const dim3 gs512(4, 96), gs1536(12, 96), gsff(16, 96), gs256(2, 96);

    // motion encoder
    sgemm_k<1, false, false, true ><<<gs512, blk, 0, stream>>>(hin, KIN, mew1t, me_b1, nullptr, nullptr, h, 512);
    sgemm_k<1, false, true,  false><<<gs512, blk, 0, stream>>>(h, 512, mew2t, me_b2, nullptr, pe15, x, 512);

    for (int i = 0; i < NLAYERS; ++i) {
        const int lo = CTXF + THRW * i;
        const int hi = (T_SEQ - 1) - THRW * i;
        int qlow_end = lo + 127;
        int qhi0 = hi - 128;
        int nlow, ninact;
        if (qhi0 <= qlow_end + 1) {
            nlow = T_SEQ; qhi0 = T_SEQ; ninact = 0;
        } else {
            nlow = qlow_end + 1;
            ninact = qhi0 - nlow;
        }
        const int tl2 = (nlow + 15) / 16;
        const int th2 = (T_SEQ - qhi0 + 15) / 16;
        const int st  = tl2 + th2;

        ln_k<<<MROWS / 4, blk, 0, stream>>>(x, ln1_g + i * 512, ln1_b + i * 512, h);
        sgemm_k<0, false, false, true><<<gs1536, blk, 0, stream>>>(h, 512, qkvt + (size_t)i * 1536 * 512, bqkv + i * 1536, nullptr, nullptr, qkv, 1536);
        if (ninact > 0) {
            vmeanp_k<<<dim3(16, 8), dim3(1024), 0, stream>>>(qkv, vmp);
            vmred_k<<<1, dim3(1024), 0, stream>>>(vmp, vm);
            vfill_k<<<dim3(ninact, NB), blk, 0, stream>>>(vm, h, nlow);
        }
        attn3_k<<<dim3((st + 3) / 4, NHEADS, NB), blk, 0, stream>>>(qkv, h, lo, hi, nlow, qhi0, tl2, st);
        sgemm_k<0, true, false, false><<<gs512, blk, 0, stream>>>(h, 512, wot + (size_t)i * 512 * 512, bo + i * 512, x, nullptr, x, 512);
        ln_k<<<MROWS / 4, blk, 0, stream>>>(x, ln2_g + i * 512, ln2_b + i * 512, h);
        sgemm_k<2, false, false, true><<<gsff, blk, 0, stream>>>(h, 512, ffn1t + (size_t)i * 2048 * 512, ffn_b1 + i * 2048, nullptr, nullptr, ff, 2048);
        sgemm_k<0, true, false, false><<<gs512, blk, 0, stream>>>(ff, 2048, ffn2t + (size_t)i * 512 * 2048, ffn_b2 + i * 512, x, nullptr, x, 512);
    }

    // decoder
    ln_k<<<MROWS / 4, blk, 0, stream>>>(x, fln_g, fln_b, h);
    sgemm_k<1, false, false, true ><<<gs512, blk, 0, stream>>>(h, 512, dec1t, dec_b1, nullptr, nullptr, ff, 512);
    sgemm_k<0, false, false, false><<<gs256, blk, 0, stream>>>(ff, 512, dec2t, dec_b2, nullptr, nullptr, xdec, 256);

    final_k<<<(MROWS * DMOTION + 255) / 256, blk, 0, stream>>>(motion, xdec, out);
}

// Round 9
// 813.389 us; speedup vs baseline: 2.1265x; 2.1265x over previous
//
#include <hip/hip_runtime.h>
#include <math.h>

typedef unsigned short ushort_t;
typedef unsigned int uint_t;
typedef __bf16 bf16x4 __attribute__((ext_vector_type(4)));
typedef __bf16 bf16x8 __attribute__((ext_vector_type(8)));
typedef float f32x4 __attribute__((ext_vector_type(4)));

#define T_SEQ   1536
#define NB      2
#define MROWS   3072
#define DMODEL  512
#define NHEADS  8
#define DHEAD   64
#define DFF     2048
#define DMOTION 256
#define NLAYERS 6
#define PERIODN 15
#define CTXF    10
#define THRW    128
#define KIN     384           // 262 zero-padded to multiple of 128

__device__ __forceinline__ float bf2f(ushort_t u) { return __uint_as_float((uint_t)u << 16); }
__device__ __forceinline__ ushort_t f2bf(float f) {
    uint_t x = __float_as_uint(f);
    return (ushort_t)((x + 0x7fffu + ((x >> 16) & 1u)) >> 16);   // RNE
}

// Direct HBM->LDS async copy, 16 B per lane. LDS dest = wave-uniform base
// + lane*16 (HW); global src is per-lane -> swizzled layouts via source.
__device__ __forceinline__ void gl2lds(const ushort_t* g, ushort_t* l) {
    __builtin_amdgcn_global_load_lds((const __attribute__((address_space(1))) void*)g,
                                     (__attribute__((address_space(3))) void*)l, 16, 0, 0);
}

// ---------------------------------------------------------------------------
// PE table (15 distinct rows)
// ---------------------------------------------------------------------------
__global__ __launch_bounds__(256) void pe_k(float* __restrict__ pe) {
    int idx = blockIdx.x * 256 + threadIdx.x;
    if (idx >= PERIODN * DMODEL) return;
    int p = idx / DMODEL, c = idx % DMODEL;
    int j = (c < DMODEL / 2) ? c : (c - DMODEL / 2);
    float div = __expf(-logf(10000.0f) * (2.0f * (float)j) / (float)DMODEL);
    float ang = (float)p * div;
    pe[idx] = (c < DMODEL / 2) ? sinf(ang) : cosf(ang);
}

// ---------------------------------------------------------------------------
// Encoder input (bf16, K padded to 384) + mask output
// ---------------------------------------------------------------------------
__global__ __launch_bounds__(256) void build_k(const float* __restrict__ motion,
                                               const float* __restrict__ traj,
                                               ushort_t* __restrict__ hin,
                                               float* __restrict__ mask_out) {
    int idx = blockIdx.x * 256 + threadIdx.x;
    if (idx >= MROWS * KIN) return;
    int row = idx / KIN, c = idx % KIN;
    int t = row % T_SEQ;
    float mv = (t < CTXF || t == T_SEQ - 1) ? 1.0f : 0.0f;
    float val;
    if (c < DMOTION)            val = motion[(size_t)row * DMOTION + c] * mv;
    else if (c < DMOTION + 5)   val = traj[(size_t)row * 5 + (c - DMOTION)];
    else if (c == DMOTION + 5)  val = mv;
    else                        val = 0.0f;
    hin[idx] = f2bf(val);
    if (c == 0) mask_out[row] = mv;
}

// ---------------------------------------------------------------------------
// Transpose-convert: src f32 [K][N] -> dst bf16 [N][Kpad] (zero pad k>=K).
// ---------------------------------------------------------------------------
__global__ __launch_bounds__(256)
void tconv_k(const float* __restrict__ src, size_t sstride,
             ushort_t* __restrict__ dst, size_t dstride,
             int K, int N, int Kpad) {
    __shared__ float t[32][33];
    src += (size_t)blockIdx.z * sstride;
    dst += (size_t)blockIdx.z * dstride;
    const int kb = blockIdx.y * 32, nb = blockIdx.x * 32;
    const int tx = threadIdx.x & 31, ty = threadIdx.x >> 5;
#pragma unroll
    for (int i = 0; i < 4; ++i) {
        int k = kb + ty + i * 8, n = nb + tx;
        t[ty + i * 8][tx] = (k < K && n < N) ? src[(size_t)k * N + n] : 0.0f;
    }
    __syncthreads();
#pragma unroll
    for (int i = 0; i < 4; ++i) {
        int n = nb + ty + i * 8, kk = kb + tx;
        if (n < N && kk < Kpad) dst[(size_t)n * Kpad + kk] = f2bf(t[tx][ty + i * 8]);
    }
}

// QKV concat transpose: z = layer*3+seg; dst = qkvt[l][seg*512 + n][k]
__global__ __launch_bounds__(256)
void tconv_qkv_k(const float* __restrict__ wq, const float* __restrict__ wk,
                 const float* __restrict__ wv, ushort_t* __restrict__ qkvt) {
    __shared__ float t[32][33];
    const int z = blockIdx.z, s = z % 3, l = z / 3;
    const float* src = (s == 0 ? wq : s == 1 ? wk : wv) + (size_t)l * DMODEL * DMODEL;
    ushort_t* dst = qkvt + (size_t)z * DMODEL * DMODEL;
    const int kb = blockIdx.y * 32, nb = blockIdx.x * 32;
    const int tx = threadIdx.x & 31, ty = threadIdx.x >> 5;
#pragma unroll
    for (int i = 0; i < 4; ++i)
        t[ty + i * 8][tx] = src[(size_t)(kb + ty + i * 8) * DMODEL + nb + tx];
    __syncthreads();
#pragma unroll
    for (int i = 0; i < 4; ++i)
        dst[(size_t)(nb + ty + i * 8) * DMODEL + kb + tx] = f2bf(t[tx][ty + i * 8]);
}

__global__ __launch_bounds__(256)
void bcat_k(const float* __restrict__ bq, const float* __restrict__ bk,
            const float* __restrict__ bv, float* __restrict__ bqkv) {
    int idx = blockIdx.x * 256 + threadIdx.x;
    if (idx >= NLAYERS * 3 * DMODEL) return;
    int l = idx / (3 * DMODEL), n = idx % (3 * DMODEL);
    int s = n >> 9, c = n & 511;
    const float* b = (s == 0 ? bq : s == 1 ? bk : bv);
    bqkv[idx] = b[l * DMODEL + c];
}

// ---------------------------------------------------------------------------
// Pipelined split-K bf16 MFMA GEMM: C[M,N] = epi(A[M,K] @ Wt[N,K]^T + bias)
// 32x64 tile, 4 waves each owning a 32-wide k-slice of a BK=128 chunk.
// Double-buffered LINEAR LDS staged by global_load_lds (zero staging VGPRs).
// Bank conflicts avoided by XOR-swizzling the SOURCE at 16B-unit granularity
// (u' = u ^ (row&15)) and applying the same XOR on ds_read (rule #21).
// One barrier per K-chunk. 2-stage cross-wave LDS reduce + fused epilogue.
// ---------------------------------------------------------------------------
#define CL  68      // f32 reduce-buffer row stride
template <int ACT, bool RES, bool PE, bool OUTBF>
__global__ __launch_bounds__(256)
void qgemm_k(const ushort_t* __restrict__ A, int K,
             const ushort_t* __restrict__ Wt,
             const float* __restrict__ bias,
             const float* __restrict__ res,
             const float* __restrict__ pe15,
             void* __restrict__ Cout, int N) {
    __shared__ ushort_t smem[2][(32 + 64) * 128];   // 2 x 24 KB, A | B, linear
    const int tid = threadIdx.x;
    const int lane = tid & 63, wid = tid >> 6;
    const int m0 = blockIdx.y * 32, n0 = blockIdx.x * 64;
    const int l4 = lane >> 4, l15 = lane & 15;
    const int lrow = lane >> 4;          // row within a 4-row stage instruction
    const int lu   = lane & 15;          // swizzled 16B-unit index u'

    f32x4 acc[2][4];
#pragma unroll
    for (int m = 0; m < 2; ++m)
#pragma unroll
        for (int n = 0; n < 4; ++n) acc[m][n] = (f32x4){0.f, 0.f, 0.f, 0.f};

    const int niter = K >> 7;                       // K multiple of 128

    // 24 stage instructions per buffer (A: 8 x 4 rows, B: 16 x 4 rows), 6/wave.
    // LDS linear; source column-unit u = u' ^ (row&15).
    auto stage = [&](int buf, int k0) {
        ushort_t* dst = &smem[buf][0];
#pragma unroll
        for (int j = 0; j < 6; ++j) {
            const int inst = wid * 6 + j;
            if (inst < 8) {
                const int row = inst * 4 + lrow;            // A row 0..31
                const int u = lu ^ (row & 15);
                gl2lds(A + (size_t)(m0 + row) * K + k0 + u * 8, dst + inst * 512);
            } else {
                const int bi = inst - 8;
                const int row = bi * 4 + lrow;              // B row 0..63
                const int u = lu ^ (row & 15);
                gl2lds(Wt + (size_t)(n0 + row) * K + k0 + u * 8,
                       dst + 32 * 128 + bi * 512);
            }
        }
    };

    // swizzled 8B+8B fragment read: row-major (row, 256B row), k-slice kbyte
    const int kbyte = wid * 64;                     // this wave's k-slice (bytes)
    auto rdfrag = [&](const ushort_t* t, int row) -> bf16x8 {
        const int off0 = kbyte + l4 * 8;
        const int off1 = kbyte + 32 + l4 * 8;
        const int a0 = row * 256 + (((off0 & ~15) ^ ((row & 15) << 4)) | (off0 & 15));
        const int a1 = row * 256 + (((off1 & ~15) ^ ((row & 15) << 4)) | (off1 & 15));
        bf16x4 lo = *(const bf16x4*)((const char*)t + a0);
        bf16x4 hi = *(const bf16x4*)((const char*)t + a1);
        return __builtin_shufflevector(lo, hi, 0, 1, 2, 3, 4, 5, 6, 7);
    };

    stage(0, 0);
    __syncthreads();                                 // buf0 staged (vmcnt drained)
    int cur = 0;
    for (int t = 0; t < niter; ++t) {
        if (t + 1 < niter) stage(cur ^ 1, (t + 1) << 7);   // issue next early
        const ushort_t* As = &smem[cur][0];
        const ushort_t* Bs = &smem[cur][32 * 128];
        bf16x8 af[2], bf[4];
#pragma unroll
        for (int m = 0; m < 2; ++m) af[m] = rdfrag(As, m * 16 + l15);
#pragma unroll
        for (int n = 0; n < 4; ++n) bf[n] = rdfrag(Bs, n * 16 + l15);
#pragma unroll
        for (int m = 0; m < 2; ++m)
#pragma unroll
            for (int n = 0; n < 4; ++n)
                acc[m][n] = __builtin_amdgcn_mfma_f32_16x16x32_bf16(af[m], bf[n], acc[m][n], 0, 0, 0);
        __syncthreads();            // next buf staged; all reads of cur done
        cur ^= 1;
    }

    // ---- cross-wave reduce: waves 2,3 write; waves 0,1 accumulate ----
    float* cb0 = (float*)&smem[0][0];                // 32 x CL
    float* cb1 = (float*)&smem[1][0];
    if (wid >= 2) {
        float* cb = (wid == 2) ? cb0 : cb1;
#pragma unroll
        for (int m = 0; m < 2; ++m)
#pragma unroll
            for (int n = 0; n < 4; ++n)
#pragma unroll
                for (int r = 0; r < 4; ++r)
                    cb[(m * 16 + l4 * 4 + r) * CL + n * 16 + l15] = acc[m][n][r];
    }
    __syncthreads();
    if (wid < 2) {
        float* cb = (wid == 0) ? cb0 : cb1;
#pragma unroll
        for (int m = 0; m < 2; ++m)
#pragma unroll
            for (int n = 0; n < 4; ++n)
#pragma unroll
                for (int r = 0; r < 4; ++r)
                    cb[(m * 16 + l4 * 4 + r) * CL + n * 16 + l15] += acc[m][n][r];
    }
    __syncthreads();

    // ---- epilogue: thread t -> row t>>3, cols (t&7)*8 .. +7 ----
    const int row = tid >> 3, c0 = (tid & 7) * 8;
    const int grow = m0 + row;
#pragma unroll
    for (int j = 0; j < 8; ++j) {
        const int gcol = n0 + c0 + j;
        float v = cb0[row * CL + c0 + j] + cb1[row * CL + c0 + j] + bias[gcol];
        if (ACT == 1) v = v >= 0.f ? v : 0.01f * v;
        else if (ACT == 2) v = fmaxf(v, 0.f);
        if (PE) v += pe15[((grow % T_SEQ) % PERIODN) * DMODEL + gcol];
        if (RES) v += res[(size_t)grow * N + gcol];
        if (OUTBF) ((ushort_t*)Cout)[(size_t)grow * N + gcol] = f2bf(v);
        else       ((float*)Cout)[(size_t)grow * N + gcol] = v;
    }
}

// ---------------------------------------------------------------------------
// LayerNorm: f32 in, bf16 out. One wave per row.
// ---------------------------------------------------------------------------
__global__ __launch_bounds__(256)
void ln_k(const float* __restrict__ X, const float* __restrict__ g,
          const float* __restrict__ b, ushort_t* __restrict__ Y) {
    const int wid = threadIdx.x >> 6, lane = threadIdx.x & 63;
    const int row = blockIdx.x * 4 + wid;
    const float* x = X + (size_t)row * DMODEL;
    float v[8], s = 0.f;
#pragma unroll
    for (int j = 0; j < 8; ++j) { v[j] = x[lane + 64 * j]; s += v[j]; }
#pragma unroll
    for (int o = 32; o; o >>= 1) s += __shfl_xor(s, o);
    const float mean = s * (1.0f / DMODEL);
    float vs = 0.f;
#pragma unroll
    for (int j = 0; j < 8; ++j) { float d = v[j] - mean; vs += d * d; }
#pragma unroll
    for (int o = 32; o; o >>= 1) vs += __shfl_xor(vs, o);
    const float inv = rsqrtf(vs * (1.0f / DMODEL) + 1e-5f);
    ushort_t* y = Y + (size_t)row * DMODEL;
#pragma unroll
    for (int j = 0; j < 8; ++j) {
        const int c = lane + 64 * j;
        y[c] = f2bf((v[j] - mean) * inv * g[c] + b[c]);
    }
}

// ---------------------------------------------------------------------------
// V-mean partials: grid (16 bh, 8 chunks), 1024 thr. 192 rows per block.
// ---------------------------------------------------------------------------
__global__ __launch_bounds__(1024)
void vmeanp_k(const ushort_t* __restrict__ qkv, float* __restrict__ vmp) {
    __shared__ float red[16][64];
    const int bh = blockIdx.x, ch = blockIdx.y;
    const int b = bh >> 3, h = bh & 7;
    const int wid = threadIdx.x >> 6, lane = threadIdx.x & 63;
    const ushort_t* Vb = qkv + (size_t)(b * T_SEQ) * 1536 + 1024 + h * 64 + lane;
    float s = 0.f;
    const int t0 = ch * 192;
    for (int t = t0 + wid; t < t0 + 192; t += 16) s += bf2f(Vb[(size_t)t * 1536]);
    red[wid][lane] = s;
    __syncthreads();
    if (wid == 0) {
        float tot = 0.f;
#pragma unroll
        for (int i = 0; i < 16; ++i) tot += red[i][lane];
        vmp[(ch * 16 + bh) * 64 + lane] = tot;
    }
}

// Reduce 8 partials -> vm[1024] (= [b][h][d]), scaled by 1/T.
__global__ __launch_bounds__(1024)
void vmred_k(const float* __restrict__ vmp, float* __restrict__ vm) {
    const int t = threadIdx.x;
    float s = 0.f;
#pragma unroll
    for (int ch = 0; ch < 8; ++ch) s += vmp[ch * 1024 + t];
    vm[t] = s * (1.0f / T_SEQ);
}

// Fill inactive rows [q0, q0+grid.x) with vmean.
__global__ __launch_bounds__(256)
void vfill_k(const float* __restrict__ vm, ushort_t* __restrict__ attout, int q0) {
    const int qrow = q0 + blockIdx.x, b = blockIdx.y;
    const int tid = threadIdx.x;
#pragma unroll
    for (int r = 0; r < 2; ++r) {
        const int c = tid + r * 256;
        attout[(size_t)(b * T_SEQ + qrow) * DMODEL + c] = f2bf(vm[b * 512 + c]);
    }
}

// ---------------------------------------------------------------------------
// MFMA flash attention. One WAVE per 16-row q-subtile of an active interval.
// Swapped operands: S^T = mfma(K,Q) -> q = lane&15; O^T = mfma(V^T, P).
// ---------------------------------------------------------------------------
#define KLD 72
#define VLD 36
__global__ __launch_bounds__(256)
void attn3_k(const ushort_t* __restrict__ qkv, ushort_t* __restrict__ attout,
             int lo, int hi, int nlow, int qhi0, int tl, int st) {
    __shared__ ushort_t klds_[4][32 * KLD];
    __shared__ ushort_t vlds_[4][64 * VLD];
    const int lane = threadIdx.x & 63, wid = threadIdx.x >> 6;
    const int s = blockIdx.x * 4 + wid;
    if (s >= st) return;
    const int h = blockIdx.y, b = blockIdx.z;
    const int l15 = lane & 15, l4 = lane >> 4;

    int qb, qend;
    if (s < tl) { qb = 16 * s;                qend = nlow - 1; }
    else        { qb = qhi0 + 16 * (s - tl);  qend = T_SEQ - 1; }
    const int nr = qend - qb;

    ushort_t* klds = klds_[wid];
    ushort_t* vlds = vlds_[wid];
    const size_t rbase = (size_t)(b * T_SEQ) * 1536;
    const int q = qb + l15;

    const int qrow_r = min(q, T_SEQ - 1);
    const ushort_t* qptr = qkv + rbase + (size_t)qrow_r * 1536 + h * 64;
    bf16x8 bq[2];
#pragma unroll
    for (int kh = 0; kh < 2; ++kh) {
        bf16x4 lo4 = *(const bf16x4*)(qptr + kh * 32 + l4 * 4);
        bf16x4 hi4 = *(const bf16x4*)(qptr + kh * 32 + 16 + l4 * 4);
        bq[kh] = __builtin_shufflevector(lo4, hi4, 0, 1, 2, 3, 4, 5, 6, 7);
    }

    const int band0 = max(0, qb - THRW);
    const int band1 = min(T_SEQ - 1, qb + 15 + THRW);
    const int i1s = band0, i1e = min(band1, lo - 1);
    const int i2s = max(band0, hi), i2e = band1;

    f32x4 O[4] = {{0.f,0.f,0.f,0.f},{0.f,0.f,0.f,0.f},{0.f,0.f,0.f,0.f},{0.f,0.f,0.f,0.f}};
    float m = -3.0e38f, lsum = 0.f;

#pragma unroll 1
    for (int seg = 0; seg < 2; ++seg) {
        const int s0 = seg ? i2s : i1s, s1 = seg ? i2e : i1e;
#pragma unroll 1
        for (int c0 = s0; c0 <= s1; c0 += 32) {
#pragma unroll
            for (int i = 0; i < 4; ++i) {
                const int idx = i * 64 + lane;
                const int row = idx >> 3, c = (idx & 7) * 8;
                const int kr = min(c0 + row, T_SEQ - 1);
                const uint4 kv = *(const uint4*)(qkv + rbase + (size_t)kr * 1536 + 512 + h * 64 + c);
                *(uint4*)&klds[row * KLD + c] = kv;
                const uint4 vv = *(const uint4*)(qkv + rbase + (size_t)kr * 1536 + 1024 + h * 64 + c);
                const ushort_t* vp = (const ushort_t*)&vv;
#pragma unroll
                for (int d = 0; d < 8; ++d) vlds[(c + d) * VLD + row] = vp[d];
            }
            f32x4 sacc[2];
#pragma unroll
            for (int ks = 0; ks < 2; ++ks) {
                f32x4 a = {0.f, 0.f, 0.f, 0.f};
#pragma unroll
                for (int kh = 0; kh < 2; ++kh) {
                    const ushort_t* kp = &klds[(16 * ks + l15) * KLD + kh * 32];
                    bf16x4 lo4 = *(const bf16x4*)(kp + l4 * 4);
                    bf16x4 hi4 = *(const bf16x4*)(kp + 16 + l4 * 4);
                    bf16x8 ak = __builtin_shufflevector(lo4, hi4, 0, 1, 2, 3, 4, 5, 6, 7);
                    a = __builtin_amdgcn_mfma_f32_16x16x32_bf16(ak, bq[kh], a, 0, 0, 0);
                }
                sacc[ks] = a;
            }
            float sv[8];
            bool vld[8];
            float cm = -3.0e38f;
#pragma unroll
            for (int ks = 0; ks < 2; ++ks)
#pragma unroll
                for (int r = 0; r < 4; ++r) {
                    const int key = c0 + 16 * ks + 4 * l4 + r;
                    const int dist = (q > key) ? (q - key) : (key - q);
                    const bool v = (dist <= THRW) && (key < lo || key >= hi) && (key < T_SEQ);
                    const int ii = ks * 4 + r;
                    sv[ii] = sacc[ks][r] * 0.125f - (float)(dist / PERIODN);
                    vld[ii] = v;
                    cm = fmaxf(cm, v ? sv[ii] : -3.0e38f);
                }
            cm = fmaxf(cm, __shfl_xor(cm, 16));
            cm = fmaxf(cm, __shfl_xor(cm, 32));
            const float mnew = fmaxf(m, cm);
            const float sc = __expf(m - mnew);
            m = mnew;
            float p[8], psum = 0.f;
#pragma unroll
            for (int ii = 0; ii < 8; ++ii) {
                p[ii] = vld[ii] ? __expf(sv[ii] - mnew) : 0.f;
                psum += p[ii];
            }
            psum += __shfl_xor(psum, 16);
            psum += __shfl_xor(psum, 32);
            lsum = lsum * sc + psum;
#pragma unroll
            for (int ds = 0; ds < 4; ++ds) O[ds] *= sc;
            bf16x8 pb;
#pragma unroll
            for (int ii = 0; ii < 8; ++ii) pb[ii] = (__bf16)p[ii];
#pragma unroll
            for (int ds = 0; ds < 4; ++ds) {
                const ushort_t* vp2 = &vlds[(16 * ds + l15) * VLD];
                bf16x4 lo4 = *(const bf16x4*)(vp2 + 4 * l4);
                bf16x4 hi4 = *(const bf16x4*)(vp2 + 16 + 4 * l4);
                bf16x8 av = __builtin_shufflevector(lo4, hi4, 0, 1, 2, 3, 4, 5, 6, 7);
                O[ds] = __builtin_amdgcn_mfma_f32_16x16x32_bf16(av, pb, O[ds], 0, 0, 0);
            }
        }
    }
    if (l15 <= nr) {
        const float inv = 1.0f / lsum;
        ushort_t* op = attout + (size_t)(b * T_SEQ + qb + l15) * DMODEL + h * 64;
#pragma unroll
        for (int ds = 0; ds < 4; ++ds)
#pragma unroll
            for (int r = 0; r < 4; ++r)
                op[16 * ds + 4 * l4 + r] = f2bf(O[ds][r] * inv);
    }
}

// ---------------------------------------------------------------------------
// Final blend
// ---------------------------------------------------------------------------
__global__ __launch_bounds__(256)
void final_k(const float* __restrict__ motion, const float* __restrict__ xdec,
             float* __restrict__ out) {
    int idx = blockIdx.x * 256 + threadIdx.x;
    if (idx >= MROWS * DMOTION) return;
    const int row = idx >> 8;
    const int t = row % T_SEQ;
    const float mv = (t < CTXF || t == T_SEQ - 1) ? 1.0f : 0.0f;
    out[idx] = motion[idx] * mv + xdec[idx] * (1.0f - mv);
}

// ---------------------------------------------------------------------------
extern "C" void kernel_launch(void* const* d_in, const int* in_sizes, int n_in,
                              void* d_out, int out_size, void* d_ws, size_t ws_size,
                              hipStream_t stream) {
    const float* motion = (const float*)d_in[0];
    const float* traj   = (const float*)d_in[1];
    const float* me_w1  = (const float*)d_in[2];
    const float* me_b1  = (const float*)d_in[3];
    const float* me_w2  = (const float*)d_in[4];
    const float* me_b2  = (const float*)d_in[5];
    const float* wq = (const float*)d_in[6];
    const float* bq = (const float*)d_in[7];
    const float* wk = (const float*)d_in[8];
    const float* bk = (const float*)d_in[9];
    const float* wv = (const float*)d_in[10];
    const float* bv = (const float*)d_in[11];
    const float* wo = (const float*)d_in[12];
    const float* bo = (const float*)d_in[13];
    const float* ln1_g = (const float*)d_in[14];
    const float* ln1_b = (const float*)d_in[15];
    const float* ffn_w1 = (const float*)d_in[16];
    const float* ffn_b1 = (const float*)d_in[17];
    const float* ffn_w2 = (const float*)d_in[18];
    const float* ffn_b2 = (const float*)d_in[19];
    const float* ln2_g = (const float*)d_in[20];
    const float* ln2_b = (const float*)d_in[21];
    const float* fln_g = (const float*)d_in[22];
    const float* fln_b = (const float*)d_in[23];
    const float* dec_w1 = (const float*)d_in[24];
    const float* dec_b1 = (const float*)d_in[25];
    const float* dec_w2 = (const float*)d_in[26];
    const float* dec_b2 = (const float*)d_in[27];

    float* out = (float*)d_out;
    float* mask_out = out + (size_t)MROWS * DMOTION;

    char* base = (char*)d_ws;
    auto alloc = [&](size_t bytes) { char* p = base; base += (bytes + 255) & ~(size_t)255; return p; };

    ushort_t* qkvt  = (ushort_t*)alloc((size_t)NLAYERS * 1536 * 512 * 2);
    ushort_t* wot   = (ushort_t*)alloc((size_t)NLAYERS * 512 * 512 * 2);
    ushort_t* ffn1t = (ushort_t*)alloc((size_t)NLAYERS * 2048 * 512 * 2);
    ushort_t* ffn2t = (ushort_t*)alloc((size_t)NLAYERS * 512 * 2048 * 2);
    ushort_t* mew1t = (ushort_t*)alloc((size_t)512 * KIN * 2);
    ushort_t* mew2t = (ushort_t*)alloc((size_t)512 * 512 * 2);
    ushort_t* dec1t = (ushort_t*)alloc((size_t)512 * 512 * 2);
    ushort_t* dec2t = (ushort_t*)alloc((size_t)256 * 512 * 2);
    float*    bqkv  = (float*)alloc((size_t)NLAYERS * 1536 * 4);
    float*    pe15  = (float*)alloc((size_t)PERIODN * DMODEL * 4);
    float*    vmp   = (float*)alloc((size_t)8 * 16 * 64 * 4);
    float*    vm    = (float*)alloc((size_t)16 * 64 * 4);
    ushort_t* hin   = (ushort_t*)alloc((size_t)MROWS * KIN * 2);
    float*    x     = (float*)alloc((size_t)MROWS * DMODEL * 4);
    ushort_t* h     = (ushort_t*)alloc((size_t)MROWS * DMODEL * 2);
    ushort_t* qkv   = (ushort_t*)alloc((size_t)MROWS * 1536 * 2);
    ushort_t* ff    = (ushort_t*)alloc((size_t)MROWS * DFF * 2);
    float*    xdec  = (float*)qkv;   // alias: qkv dead after last attn

    const dim3 blk(256);
    pe_k<<<(PERIODN * DMODEL + 255) / 256, blk, 0, stream>>>(pe15);
    build_k<<<(MROWS * KIN + 255) / 256, blk, 0, stream>>>(motion, traj, hin, mask_out);

    tconv_qkv_k<<<dim3(16, 16, 18), blk, 0, stream>>>(wq, wk, wv, qkvt);
    tconv_k<<<dim3(16, 16, 6), blk, 0, stream>>>(wo, 512 * 512, wot, 512 * 512, 512, 512, 512);
    tconv_k<<<dim3(64, 16, 6), blk, 0, stream>>>(ffn_w1, 512 * 2048, ffn1t, 2048 * 512, 512, 2048, 512);
    tconv_k<<<dim3(16, 64, 6), blk, 0, stream>>>(ffn_w2, 2048 * 512, ffn2t, 512 * 2048, 2048, 512, 2048);
    tconv_k<<<dim3(16, 12, 1), blk, 0, stream>>>(me_w1, 0, mew1t, 0, 262, 512, KIN);
    tconv_k<<<dim3(16, 16, 1), blk, 0, stream>>>(me_w2, 0, mew2t, 0, 512, 512, 512);
    tconv_k<<<dim3(16, 16, 1), blk, 0, stream>>>(dec_w1, 0, dec1t, 0, 512, 512, 512);
    tconv_k<<<dim3(8, 16, 1),  blk, 0, stream>>>(dec_w2, 0, dec2t, 0, 512, 256, 512);
    bcat_k<<<(NLAYERS * 1536 + 255) / 256, blk, 0, stream>>>(bq, bk, bv, bqkv);

    const dim3 gs512(8, 96), gs1536(24, 96), gsff(32, 96), gs256(4, 96);

    // motion encoder
    qgemm_k<1, false, false, true ><<<gs512, blk, 0, stream>>>(hin, KIN, mew1t, me_b1, nullptr, nullptr, h, 512);
    qgemm_k<1, false, true,  false><<<gs512, blk, 0, stream>>>(h, 512, mew2t, me_b2, nullptr, pe15, x, 512);

    for (int i = 0; i < NLAYERS; ++i) {
        const int lo = CTXF + THRW * i;
        const int hi = (T_SEQ - 1) - THRW * i;
        int qlow_end = lo + 127;
        int qhi0 = hi - 128;
        int nlow, ninact;
        if (qhi0 <= qlow_end + 1) {
            nlow = T_SEQ; qhi0 = T_SEQ; ninact = 0;
        } else {
            nlow = qlow_end + 1;
            ninact = qhi0 - nlow;
        }
        const int tl2 = (nlow + 15) / 16;
        const int th2 = (T_SEQ - qhi0 + 15) / 16;
        const int st  = tl2 + th2;

        ln_k<<<MROWS / 4, blk, 0, stream>>>(x, ln1_g + i * 512, ln1_b + i * 512, h);
        qgemm_k<0, false, false, true><<<gs1536, blk, 0, stream>>>(h, 512, qkvt + (size_t)i * 1536 * 512, bqkv + i * 1536, nullptr, nullptr, qkv, 1536);
        if (ninact > 0) {
            vmeanp_k<<<dim3(16, 8), dim3(1024), 0, stream>>>(qkv, vmp);
            vmred_k<<<1, dim3(1024), 0, stream>>>(vmp, vm);
            vfill_k<<<dim3(ninact, NB), blk, 0, stream>>>(vm, h, nlow);
        }
        attn3_k<<<dim3((st + 3) / 4, NHEADS, NB), blk, 0, stream>>>(qkv, h, lo, hi, nlow, qhi0, tl2, st);
        qgemm_k<0, true, false, false><<<gs512, blk, 0, stream>>>(h, 512, wot + (size_t)i * 512 * 512, bo + i * 512, x, nullptr, x, 512);
        ln_k<<<MROWS / 4, blk, 0, stream>>>(x, ln2_g + i * 512, ln2_b + i * 512, h);
        qgemm_k<2, false, false, true><<<gsff, blk, 0, stream>>>(h, 512, ffn1t + (size_t)i * 2048 * 512, ffn_b1 + i * 2048, nullptr, nullptr, ff, 2048);
        qgemm_k<0, true, false, false><<<gs512, blk, 0, stream>>>(ff, 2048, ffn2t + (size_t)i * 512 * 2048, ffn_b2 + i * 512, x, nullptr, x, 512);
    }

    // decoder
    ln_k<<<MROWS / 4, blk, 0, stream>>>(x, fln_g, fln_b, h);
    qgemm_k<1, false, false, true ><<<gs512, blk, 0, stream>>>(h, 512, dec1t, dec_b1, nullptr, nullptr, ff, 512);
    qgemm_k<0, false, false, false><<<gs256, blk, 0, stream>>>(ff, 512, dec2t, dec_b2, nullptr, nullptr, xdec, 256);

    final_k<<<(MROWS * DMOTION + 255) / 256, blk, 0, stream>>>(motion, xdec, out);
}